// Round 1
// baseline (681.304 us; speedup 1.0000x reference)
//
#include <hip/hip_runtime.h>

// Fixed problem sizes
#define HID 2048
#define SEQL 4096
#define CHUNK 2048
#define NHEADS 8
#define NKVH 4
#define HDIM 256

typedef __bf16 bf16x4 __attribute__((ext_vector_type(4)));
typedef __bf16 bf16x8 __attribute__((ext_vector_type(8)));
typedef float f32x4 __attribute__((ext_vector_type(4)));
typedef __attribute__((address_space(1))) unsigned int* as1_u32;
typedef __attribute__((address_space(3))) unsigned int* as3_u32;

// async global->LDS, 16B per lane; LDS dest = uniform base + lane*16
__device__ __forceinline__ void load_lds16(const __bf16* g, __bf16* l) {
  __builtin_amdgcn_global_load_lds((as1_u32)g, (as3_u32)l, 16, 0, 0);
}

// ---------- fp32 -> bf16 convert (4 elems/thread) ----------
__global__ void cvt_bf16_kernel(const float* __restrict__ X, __bf16* __restrict__ Y) {
  int i = blockIdx.x * blockDim.x + threadIdx.x;
  const float4* xv = (const float4*)X;
  float4 v = xv[i];
  bf16x4 o;
  o[0] = (__bf16)v.x; o[1] = (__bf16)v.y; o[2] = (__bf16)v.z; o[3] = (__bf16)v.w;
  *(bf16x4*)(Y + i * 4) = o;
}

// ---------- W (RxC f32, row-major) -> WT (CxR bf16) ----------
__global__ void transpose_cvt_kernel(const float* __restrict__ W, __bf16* __restrict__ WT,
                                     int R, int C) {
  __shared__ float tile[64][65];
  int r0 = blockIdx.y * 64, c0 = blockIdx.x * 64;
  for (int i = threadIdx.x; i < 4096; i += 256) {
    int r = i >> 6, c = i & 63;
    tile[r][c] = W[(r0 + r) * C + c0 + c];
  }
  __syncthreads();
  for (int i = threadIdx.x; i < 4096; i += 256) {
    int c = i >> 6, r = i & 63;
    WT[(c0 + c) * R + r0 + r] = (__bf16)tile[r][c];
  }
}

// ---------- C(MxN) = A(MxK) @ B^T(NxK), bf16 in, fp32 acc ----------
// m97 pattern: 128x128 tile, BK=32, global_load_lds(16B), 16x16x32 bf16 MFMA
template <bool F32OUT>
__global__ __launch_bounds__(256, 2) void gemm_bt_kernel(
    const __bf16* __restrict__ A, const __bf16* __restrict__ B,
    void* __restrict__ Cv, int M, int N, int Kd) {
  __shared__ __bf16 Asm[128 * 32];
  __shared__ __bf16 Bsm[128 * 32];
  const int tid = threadIdx.x;
  const int lane = tid & 63, wave = tid >> 6;
  const int quad = lane >> 4, l15 = lane & 15;
  const int m0 = blockIdx.x * 128, n0 = blockIdx.y * 128;
  const int wm = (wave & 1) * 64, wn = (wave >> 1) * 64;
  f32x4 acc[4][4];
#pragma unroll
  for (int i = 0; i < 4; i++)
#pragma unroll
    for (int j = 0; j < 4; j++) acc[i][j] = (f32x4){0.f, 0.f, 0.f, 0.f};

  const int c0 = wave, c1 = wave + 4;
  const __bf16* ga0 = A + (m0 + c0 * 16 + (lane >> 2)) * Kd + (lane & 3) * 8;
  const __bf16* ga1 = A + (m0 + c1 * 16 + (lane >> 2)) * Kd + (lane & 3) * 8;
  const __bf16* gb0 = B + (n0 + c0 * 16 + (lane >> 2)) * Kd + (lane & 3) * 8;
  const __bf16* gb1 = B + (n0 + c1 * 16 + (lane >> 2)) * Kd + (lane & 3) * 8;
  __bf16* la0 = Asm + c0 * 512;
  __bf16* la1 = Asm + c1 * 512;
  __bf16* lb0 = Bsm + c0 * 512;
  __bf16* lb1 = Bsm + c1 * 512;

  for (int k0 = 0; k0 < Kd; k0 += 32) {
    load_lds16(ga0 + k0, la0);
    load_lds16(ga1 + k0, la1);
    load_lds16(gb0 + k0, lb0);
    load_lds16(gb1 + k0, lb1);
    __syncthreads();
    bf16x8 af[4], bfr[4];
#pragma unroll
    for (int i = 0; i < 4; i++) {
      af[i] = *(const bf16x8*)(Asm + (wm + i * 16 + l15) * 32 + quad * 8);
      bfr[i] = *(const bf16x8*)(Bsm + (wn + i * 16 + l15) * 32 + quad * 8);
    }
#pragma unroll
    for (int mi = 0; mi < 4; mi++)
#pragma unroll
      for (int ni = 0; ni < 4; ni++)
        acc[mi][ni] = __builtin_amdgcn_mfma_f32_16x16x32_bf16(af[mi], bfr[ni], acc[mi][ni], 0, 0, 0);
    __syncthreads();
  }
#pragma unroll
  for (int mi = 0; mi < 4; mi++) {
    int r = m0 + wm + mi * 16 + quad * 4;
#pragma unroll
    for (int ni = 0; ni < 4; ni++) {
      int cc = n0 + wn + ni * 16 + l15;
#pragma unroll
      for (int j = 0; j < 4; j++) {
        if (F32OUT)
          ((float*)Cv)[(r + j) * N + cc] = acc[mi][ni][j];
        else
          ((__bf16*)Cv)[(r + j) * N + cc] = (__bf16)acc[mi][ni][j];
      }
    }
  }
}

// ---------- RMSNorm (+RoPE) per (token, head); one wave per row ----------
// MODE 0: Q (rope, pos=t+2048, H=8, in-place)
// MODE 1: K (rope, pos=t,      H=4, in-place)
// MODE 2: V (norm only, H=4, write transposed VT[h][d][t])
template <int MODE>
__global__ void norm_rope_kernel(__bf16* __restrict__ X, __bf16* __restrict__ VT,
                                 const float* __restrict__ cosb, const float* __restrict__ sinb,
                                 const float* __restrict__ w) {
  const int gw = (blockIdx.x * 256 + threadIdx.x) >> 6;
  const int lane = threadIdx.x & 63;
  const int H = (MODE == 0) ? 8 : 4;
  const int t = gw / H, h = gw % H;
  __bf16* row = X + (t * H + h) * 256;
  const int d0 = lane * 4;
  bf16x4 rv = *(const bf16x4*)(row + d0);
  float x[4];
  float ss = 0.f;
#pragma unroll
  for (int j = 0; j < 4; j++) { x[j] = (float)rv[j]; ss += x[j] * x[j]; }
#pragma unroll
  for (int off = 1; off < 64; off <<= 1) ss += __shfl_xor(ss, off);
  float scale = rsqrtf(ss * (1.f / 256.f) + 1e-6f);
  float n[4];
#pragma unroll
  for (int j = 0; j < 4; j++) n[j] = x[j] * scale * (1.f + w[d0 + j]);
  if (MODE < 2) {
    const int pos = t + (MODE == 0 ? 2048 : 0);
    const float* cp = cosb + pos * 256 + d0;
    const float* sp = sinb + pos * 256 + d0;
    bf16x4 ov;
#pragma unroll
    for (int j = 0; j < 4; j++) {
      float other = __shfl_xor(n[j], 32);           // d and d^128 live in lane^32
      float rot = (lane < 32) ? -other : other;     // rotate_half sign
      ov[j] = (__bf16)(n[j] * cp[j] + rot * sp[j]);
    }
    *(bf16x4*)(row + d0) = ov;
  } else {
#pragma unroll
    for (int j = 0; j < 4; j++)
      VT[h * (256 * 4096) + (d0 + j) * 4096 + t] = (__bf16)n[j];
  }
}

// ---------- flash attention: block = 1 head x 64 queries, 4 waves x 16 rows ----------
__global__ __launch_bounds__(256, 2) void attn_kernel(
    const __bf16* __restrict__ Q,   // [2048][8*256] post norm+rope
    const __bf16* __restrict__ K,   // [4096][4*256] post norm+rope
    const __bf16* __restrict__ VT,  // [4][256][4096] post norm, transposed
    __bf16* __restrict__ AO) {      // [2048][8*256]
  __shared__ __bf16 Ksm[8][32][32];   // [kstep-panel][key][k] 16KB, glds layout
  __shared__ __bf16 Vsm[256][32];     // [d][key] 16KB, glds layout
  __shared__ __bf16 Pex[4][16][40];   // P C->A layout exchange, stride 40 (2-way bank only)
  const int tid = threadIdx.x;
  const int lane = tid & 63, wave = tid >> 6;
  const int quad = lane >> 4, l15 = lane & 15;
  const int h = blockIdx.x & 7, qt = blockIdx.x >> 3;
  const int kvh = h >> 1;

  bf16x8 qf[8];
  {
    const __bf16* qp = Q + (qt * 64 + wave * 16 + l15) * 2048 + h * 256 + quad * 8;
#pragma unroll
    for (int s = 0; s < 8; s++) qf[s] = *(const bf16x8*)(qp + s * 32);
  }
  f32x4 o[16];
#pragma unroll
  for (int i = 0; i < 16; i++) o[i] = (f32x4){0.f, 0.f, 0.f, 0.f};
  float m_i[4], l_i[4];
#pragma unroll
  for (int j = 0; j < 4; j++) { m_i[j] = -1e30f; l_i[j] = 0.f; }

  const int nsteps = 66 + 2 * qt;  // covers keys up to 2048 + qt*64 + 63
  const __bf16* Kb = K + kvh * 256;
  const __bf16* Vb = VT + kvh * (256 * 4096);
  const int qrow = 2048 + qt * 64 + wave * 16 + quad * 4;  // + j

  for (int kv = 0; kv < nsteps; kv++) {
    const int t0 = kv * 32;
#pragma unroll
    for (int ch = 0; ch < 4; ch++) {  // K tile: 16 x 1KB chunks
      int cc = wave + ch * 4;
      int s = cc >> 1, half = cc & 1;
      const __bf16* g = Kb + (t0 + half * 16 + (lane >> 2)) * 1024 + s * 32 + (lane & 3) * 8;
      load_lds16(g, &Ksm[s][half * 16][0]);
    }
#pragma unroll
    for (int ch = 0; ch < 4; ch++) {  // V tile: 16 x 1KB chunks
      int cc = wave + ch * 4;
      const __bf16* g = Vb + (cc * 16 + (lane >> 2)) * 4096 + t0 + (lane & 3) * 8;
      load_lds16(g, &Vsm[cc * 16][0]);
    }
    __syncthreads();

    // S = Q K^T (16 x 32 per wave)
    f32x4 s4[2];
    s4[0] = (f32x4){0.f, 0.f, 0.f, 0.f};
    s4[1] = s4[0];
#pragma unroll
    for (int s = 0; s < 8; s++) {
      bf16x8 b0 = *(const bf16x8*)(&Ksm[s][l15][quad * 8]);
      bf16x8 b1 = *(const bf16x8*)(&Ksm[s][16 + l15][quad * 8]);
      s4[0] = __builtin_amdgcn_mfma_f32_16x16x32_bf16(qf[s], b0, s4[0], 0, 0, 0);
      s4[1] = __builtin_amdgcn_mfma_f32_16x16x32_bf16(qf[s], b1, s4[1], 0, 0, 0);
    }

    // scale + softcap + causal mask + block row-max
    float bm[4] = {-1e30f, -1e30f, -1e30f, -1e30f};
#pragma unroll
    for (int nt = 0; nt < 2; nt++) {
      const int key = t0 + nt * 16 + l15;
#pragma unroll
      for (int j = 0; j < 4; j++) {
        float v = s4[nt][j] * 0.0625f;                 // * HEAD_DIM^-0.5
        float e = __expf(v * 0.04f);                   // e^{2v/50}
        v = 50.f - 100.f / (e + 1.f);                  // 50*tanh(v/50)
        if (key > qrow + j) v = -1e30f;
        s4[nt][j] = v;
        bm[j] = fmaxf(bm[j], v);
      }
    }
#pragma unroll
    for (int off = 1; off < 16; off <<= 1)
#pragma unroll
      for (int j = 0; j < 4; j++) bm[j] = fmaxf(bm[j], __shfl_xor(bm[j], off));

    float alpha[4];
    int need = 0;
#pragma unroll
    for (int j = 0; j < 4; j++) {
      float nm = fmaxf(m_i[j], bm[j]);
      alpha[j] = __expf(m_i[j] - nm);
      if (bm[j] > m_i[j]) need = 1;
      m_i[j] = nm;
    }
    if (__any(need)) {  // skip O rescale when max unchanged (alpha==1 exactly)
#pragma unroll
      for (int i = 0; i < 16; i++)
#pragma unroll
        for (int j = 0; j < 4; j++) o[i][j] *= alpha[j];
    }

    float rs[4] = {0.f, 0.f, 0.f, 0.f};
#pragma unroll
    for (int nt = 0; nt < 2; nt++)
#pragma unroll
      for (int j = 0; j < 4; j++) {
        float p = __expf(s4[nt][j] - m_i[j]);
        s4[nt][j] = p;
        rs[j] += p;
      }
#pragma unroll
    for (int off = 1; off < 16; off <<= 1)
#pragma unroll
      for (int j = 0; j < 4; j++) rs[j] += __shfl_xor(rs[j], off);
#pragma unroll
    for (int j = 0; j < 4; j++) l_i[j] = l_i[j] * alpha[j] + rs[j];

    // P: C-layout -> LDS -> A-layout
#pragma unroll
    for (int nt = 0; nt < 2; nt++)
#pragma unroll
      for (int j = 0; j < 4; j++)
        Pex[wave][quad * 4 + j][nt * 16 + l15] = (__bf16)s4[nt][j];
    __syncthreads();

    bf16x8 pf = *(const bf16x8*)(&Pex[wave][l15][quad * 8]);
#pragma unroll
    for (int d = 0; d < 16; d++) {
      bf16x8 vf = *(const bf16x8*)(&Vsm[d * 16 + l15][quad * 8]);
      o[d] = __builtin_amdgcn_mfma_f32_16x16x32_bf16(pf, vf, o[d], 0, 0, 0);
    }
    __syncthreads();
  }

  float inv[4];
#pragma unroll
  for (int j = 0; j < 4; j++) inv[j] = 1.f / l_i[j];
  const int trow = qt * 64 + wave * 16 + quad * 4;
#pragma unroll
  for (int d = 0; d < 16; d++) {
    const int col = h * 256 + d * 16 + l15;
#pragma unroll
    for (int j = 0; j < 4; j++)
      AO[(trow + j) * 2048 + col] = (__bf16)(o[d][j] * inv[j]);
  }
}

extern "C" void kernel_launch(void* const* d_in, const int* in_sizes, int n_in,
                              void* d_out, int out_size, void* d_ws, size_t ws_size,
                              hipStream_t stream) {
  const float* hidden = (const float*)d_in[0];
  const float* cosb = (const float*)d_in[1];
  const float* sinb = (const float*)d_in[2];
  // d_in[3] attention_mask: causal, reproduced analytically
  const float* wq = (const float*)d_in[4];
  const float* wk = (const float*)d_in[5];
  const float* wv = (const float*)d_in[6];
  const float* wo = (const float*)d_in[7];
  const float* qw = (const float*)d_in[8];
  const float* kw = (const float*)d_in[9];
  const float* vw = (const float*)d_in[10];
  float* outp = (float*)d_out;

  char* p = (char*)d_ws;
  __bf16* Xb = (__bf16*)p;  p += (size_t)SEQL * HID * 2;       // 16 MB
  __bf16* WQT = (__bf16*)p; p += (size_t)2048 * 2048 * 2;      // 8 MB
  __bf16* WKT = (__bf16*)p; p += (size_t)1024 * 2048 * 2;      // 4 MB
  __bf16* WVT = (__bf16*)p; p += (size_t)1024 * 2048 * 2;      // 4 MB
  __bf16* WOT = (__bf16*)p; p += (size_t)2048 * 2048 * 2;      // 8 MB
  __bf16* Qp = (__bf16*)p;  p += (size_t)2048 * 2048 * 2;      // 8 MB
  __bf16* Kp = (__bf16*)p;  p += (size_t)4096 * 1024 * 2;      // 8 MB
  __bf16* Vp = (__bf16*)p;  p += (size_t)4096 * 1024 * 2;      // 8 MB
  __bf16* VT = (__bf16*)p;  p += (size_t)4 * 256 * 4096 * 2;   // 8 MB
  __bf16* AO = (__bf16*)p;  p += (size_t)2048 * 2048 * 2;      // 8 MB  (total 84 MB)

  // 1) convert inputs / weights to bf16 (weights transposed to NxK)
  cvt_bf16_kernel<<<8192, 256, 0, stream>>>(hidden, Xb);
  transpose_cvt_kernel<<<dim3(32, 32), 256, 0, stream>>>(wq, WQT, 2048, 2048);
  transpose_cvt_kernel<<<dim3(16, 32), 256, 0, stream>>>(wk, WKT, 2048, 1024);
  transpose_cvt_kernel<<<dim3(16, 32), 256, 0, stream>>>(wv, WVT, 2048, 1024);
  transpose_cvt_kernel<<<dim3(32, 32), 256, 0, stream>>>(wo, WOT, 2048, 2048);

  // 2) projections (bf16 MFMA, fp32 acc)
  gemm_bt_kernel<false><<<dim3(16, 16), 256, 0, stream>>>(Xb + 2048 * 2048, WQT, Qp, 2048, 2048, 2048);
  gemm_bt_kernel<false><<<dim3(32, 8), 256, 0, stream>>>(Xb, WKT, Kp, 4096, 1024, 2048);
  gemm_bt_kernel<false><<<dim3(32, 8), 256, 0, stream>>>(Xb, WVT, Vp, 4096, 1024, 2048);

  // 3) RMSNorm (+RoPE); V also transposed for PV fragments
  norm_rope_kernel<0><<<4096, 256, 0, stream>>>(Qp, nullptr, cosb, sinb, qw);
  norm_rope_kernel<1><<<4096, 256, 0, stream>>>(Kp, nullptr, cosb, sinb, kw);
  norm_rope_kernel<2><<<4096, 256, 0, stream>>>(Vp, VT, cosb, sinb, vw);

  // 4) flash attention (softcap + causal + online softmax)
  attn_kernel<<<256, 256, 0, stream>>>(Qp, Kp, VT, AO);

  // 5) output projection -> fp32
  gemm_bt_kernel<true><<<dim3(16, 16), 256, 0, stream>>>(AO, WOT, outp, 2048, 2048, 2048);
}

// Round 2
// 489.066 us; speedup vs baseline: 1.3931x; 1.3931x over previous
//
#include <hip/hip_runtime.h>

// Fixed problem sizes
#define HID 2048
#define SEQL 4096
#define CHUNK 2048
#define NHEADS 8
#define NKVH 4
#define HDIM 256

typedef __bf16 bf16x4 __attribute__((ext_vector_type(4)));
typedef __bf16 bf16x8 __attribute__((ext_vector_type(8)));
typedef float f32x4 __attribute__((ext_vector_type(4)));
typedef __attribute__((address_space(1))) unsigned int* as1_u32;
typedef __attribute__((address_space(3))) unsigned int* as3_u32;

// async global->LDS, 16B per lane; LDS dest = uniform base + lane*16
__device__ __forceinline__ void load_lds16(const __bf16* g, __bf16* l) {
  __builtin_amdgcn_global_load_lds((as1_u32)g, (as3_u32)l, 16, 0, 0);
}

// ---------- fp32 -> bf16 convert (4 elems/thread) ----------
__global__ void cvt_bf16_kernel(const float* __restrict__ X, __bf16* __restrict__ Y) {
  int i = blockIdx.x * blockDim.x + threadIdx.x;
  const float4* xv = (const float4*)X;
  float4 v = xv[i];
  bf16x4 o;
  o[0] = (__bf16)v.x; o[1] = (__bf16)v.y; o[2] = (__bf16)v.z; o[3] = (__bf16)v.w;
  *(bf16x4*)(Y + i * 4) = o;
}

// ---------- W (RxC f32, row-major) -> WT (CxR bf16), WT row stride = R ----------
__global__ void transpose_cvt_kernel(const float* __restrict__ W, __bf16* __restrict__ WT,
                                     int R, int C) {
  __shared__ float tile[64][65];
  int r0 = blockIdx.y * 64, c0 = blockIdx.x * 64;
  for (int i = threadIdx.x; i < 4096; i += 256) {
    int r = i >> 6, c = i & 63;
    tile[r][c] = W[(r0 + r) * C + c0 + c];
  }
  __syncthreads();
  for (int i = threadIdx.x; i < 4096; i += 256) {
    int c = i >> 6, r = i & 63;
    WT[(c0 + c) * R + r0 + r] = (__bf16)tile[r][c];
  }
}

// ---------- C(MxN) = A(MxK) @ B^T(NxK), bf16 in, fp32 acc ----------
// m97 pattern; tile 128 x (NI*32); NI=4 -> 128x128, NI=2 -> 128x64
template <int NI, bool F32OUT>
__global__ __launch_bounds__(256, 2) void gemm_bt_kernel(
    const __bf16* __restrict__ A, const __bf16* __restrict__ B,
    void* __restrict__ Cv, int M, int N, int Kd) {
  constexpr int BN = NI * 32;
  __shared__ __bf16 Asm[128 * 32];
  __shared__ __bf16 Bsm[BN * 32];
  const int tid = threadIdx.x;
  const int lane = tid & 63, wave = tid >> 6;
  const int quad = lane >> 4, l15 = lane & 15;
  const int m0 = blockIdx.x * 128, n0 = blockIdx.y * BN;
  const int wm = (wave & 1) * 64, wn = (wave >> 1) * (NI * 16);
  f32x4 acc[4][NI];
#pragma unroll
  for (int i = 0; i < 4; i++)
#pragma unroll
    for (int j = 0; j < NI; j++) acc[i][j] = (f32x4){0.f, 0.f, 0.f, 0.f};

  const int rA = lane >> 2, cA = (lane & 3) * 8;

  for (int k0 = 0; k0 < Kd; k0 += 32) {
#pragma unroll
    for (int c = wave; c < 8; c += 4)
      load_lds16(A + (size_t)(m0 + c * 16 + rA) * Kd + k0 + cA, Asm + c * 512);
#pragma unroll
    for (int c = wave; c < BN / 16; c += 4)
      load_lds16(B + (size_t)(n0 + c * 16 + rA) * Kd + k0 + cA, Bsm + c * 512);
    __syncthreads();
    bf16x8 af[4], bfr[NI];
#pragma unroll
    for (int i = 0; i < 4; i++)
      af[i] = *(const bf16x8*)(Asm + (wm + i * 16 + l15) * 32 + quad * 8);
#pragma unroll
    for (int i = 0; i < NI; i++)
      bfr[i] = *(const bf16x8*)(Bsm + (wn + i * 16 + l15) * 32 + quad * 8);
#pragma unroll
    for (int mi = 0; mi < 4; mi++)
#pragma unroll
      for (int ni = 0; ni < NI; ni++)
        acc[mi][ni] = __builtin_amdgcn_mfma_f32_16x16x32_bf16(af[mi], bfr[ni], acc[mi][ni], 0, 0, 0);
    __syncthreads();
  }
#pragma unroll
  for (int mi = 0; mi < 4; mi++) {
    int r = m0 + wm + mi * 16 + quad * 4;
#pragma unroll
    for (int ni = 0; ni < NI; ni++) {
      int cc = n0 + wn + ni * 16 + l15;
#pragma unroll
      for (int j = 0; j < 4; j++) {
        if (F32OUT)
          ((float*)Cv)[(size_t)(r + j) * N + cc] = acc[mi][ni][j];
        else
          ((__bf16*)Cv)[(size_t)(r + j) * N + cc] = (__bf16)acc[mi][ni][j];
      }
    }
  }
}

// ---------- RMSNorm (+RoPE) per (token, head); one wave per row ----------
// MODE 0: Q (rope, pos=t+2048, H=8, in-place, prescaled by 2^-4)
// MODE 1: K (rope, pos=t,      H=4, in-place)
// MODE 2: V (norm only, H=4, write transposed VT[h][d][t])
template <int MODE>
__global__ void norm_rope_kernel(__bf16* __restrict__ X, int RS, __bf16* __restrict__ VT,
                                 const float* __restrict__ cosb, const float* __restrict__ sinb,
                                 const float* __restrict__ w) {
  const int gw = (blockIdx.x * 256 + threadIdx.x) >> 6;
  const int lane = threadIdx.x & 63;
  const int H = (MODE == 0) ? 8 : 4;
  const int t = gw / H, h = gw % H;
  __bf16* row = X + (size_t)t * RS + h * 256;
  const int d0 = lane * 4;
  bf16x4 rv = *(const bf16x4*)(row + d0);
  float x[4];
  float ss = 0.f;
#pragma unroll
  for (int j = 0; j < 4; j++) { x[j] = (float)rv[j]; ss += x[j] * x[j]; }
#pragma unroll
  for (int off = 1; off < 64; off <<= 1) ss += __shfl_xor(ss, off);
  float scale = rsqrtf(ss * (1.f / 256.f) + 1e-6f);
  float n[4];
#pragma unroll
  for (int j = 0; j < 4; j++) n[j] = x[j] * scale * (1.f + w[d0 + j]);
  if (MODE < 2) {
    const int pos = t + (MODE == 0 ? 2048 : 0);
    const float* cp = cosb + pos * 256 + d0;
    const float* sp = sinb + pos * 256 + d0;
    bf16x4 ov;
#pragma unroll
    for (int j = 0; j < 4; j++) {
      float other = __shfl_xor(n[j], 32);           // d and d^128 live in lane^32
      float rot = (lane < 32) ? -other : other;     // rotate_half sign
      float r = n[j] * cp[j] + rot * sp[j];
      if (MODE == 0) r *= 0.0625f;                  // fold HEAD_DIM^-0.5 (exact pow2)
      ov[j] = (__bf16)r;
    }
    *(bf16x4*)(row + d0) = ov;
  } else {
#pragma unroll
    for (int j = 0; j < 4; j++)
      VT[(size_t)h * (256 * 4096) + (size_t)(d0 + j) * 4096 + t] = (__bf16)n[j];
  }
}

// ---------- flash attention, fixed softmax max (softcap bounds logits to +-50) ----------
// grid 512: b -> sp = b&1 (KV split), h = (b>>1)&7, qt = b>>4. 4 waves x 16 q-rows.
// Double-buffered K/V LDS, one barrier per 32-key step. Partial O (fp32, unnormalized)
// and partial l per split; merged by merge_kernel.
__global__ __launch_bounds__(256, 2) void attn_kernel(
    const __bf16* __restrict__ Q,   // [2048][8*256] post norm+rope, prescaled 2^-4
    const __bf16* __restrict__ K,   // [4096][2048] cols 0..1023 = K heads (post norm+rope)
    const __bf16* __restrict__ VT,  // [4][256][4096] post norm, transposed
    float* __restrict__ Op,         // [2][2048][2048] partial O
    float* __restrict__ Lp) {       // [2][2048][8]    partial l
  __shared__ __bf16 Ksm[2][8][32][32];  // 32 KB  [buf][k-panel][key][k]
  __shared__ __bf16 Vsm[2][256][32];    // 32 KB  [buf][d][key]
  __shared__ __bf16 Pex[4][16][40];     // 5 KB   per-wave P C->A exchange
  const int tid = threadIdx.x;
  const int lane = tid & 63, wave = tid >> 6;
  const int quad = lane >> 4, l15 = lane & 15;
  const int b = blockIdx.x;
  const int sp = b & 1, h = (b >> 1) & 7, qt = b >> 4;
  const int kvh = h >> 1;

  const int T = 66 + 2 * qt;            // total 32-key steps for this q-tile
  const int half = T >> 1;
  const int s0 = sp ? half : 0;
  const int nst = sp ? (T - half) : half;

  bf16x8 qf[8];
  {
    const __bf16* qp = Q + (size_t)(qt * 64 + wave * 16 + l15) * 2048 + h * 256 + quad * 8;
#pragma unroll
    for (int s = 0; s < 8; s++) qf[s] = *(const bf16x8*)(qp + s * 32);
  }
  f32x4 o[16];
#pragma unroll
  for (int i = 0; i < 16; i++) o[i] = (f32x4){0.f, 0.f, 0.f, 0.f};
  float rs[4] = {0.f, 0.f, 0.f, 0.f};

  const __bf16* Kb = K + kvh * 256;
  const __bf16* Vb = VT + (size_t)kvh * (256 * 4096);
  const int rA = lane >> 2, cA = (lane & 3) * 8;
  const int qrow = 2048 + qt * 64 + wave * 16 + quad * 4;  // + j

  // stage step s0 into buf 0
  {
    const int t0 = s0 * 32;
#pragma unroll
    for (int ch = 0; ch < 4; ch++) {
      int cc = wave + ch * 4;
      int s = cc >> 1, hf = cc & 1;
      load_lds16(Kb + (size_t)(t0 + hf * 16 + rA) * 2048 + s * 32 + cA, &Ksm[0][s][hf * 16][0]);
      load_lds16(Vb + (size_t)(cc * 16 + rA) * 4096 + t0 + cA, &Vsm[0][cc * 16][0]);
    }
  }

  for (int i = 0; i < nst; i++) {
    const int buf = i & 1;
    const int t0 = (s0 + i) * 32;
    __syncthreads();  // drains vmcnt: buf ready; all waves done with other buf
    if (i + 1 < nst) {
      const int t1 = t0 + 32;
#pragma unroll
      for (int ch = 0; ch < 4; ch++) {
        int cc = wave + ch * 4;
        int s = cc >> 1, hf = cc & 1;
        load_lds16(Kb + (size_t)(t1 + hf * 16 + rA) * 2048 + s * 32 + cA, &Ksm[buf ^ 1][s][hf * 16][0]);
        load_lds16(Vb + (size_t)(cc * 16 + rA) * 4096 + t1 + cA, &Vsm[buf ^ 1][cc * 16][0]);
      }
    }

    // S = Q K^T (16 x 32 per wave); Q prescaled so S is the scaled logit
    f32x4 s4[2];
    s4[0] = (f32x4){0.f, 0.f, 0.f, 0.f};
    s4[1] = s4[0];
#pragma unroll
    for (int s = 0; s < 8; s++) {
      bf16x8 b0 = *(const bf16x8*)(&Ksm[buf][s][l15][quad * 8]);
      bf16x8 b1 = *(const bf16x8*)(&Ksm[buf][s][16 + l15][quad * 8]);
      s4[0] = __builtin_amdgcn_mfma_f32_16x16x32_bf16(qf[s], b0, s4[0], 0, 0, 0);
      s4[1] = __builtin_amdgcn_mfma_f32_16x16x32_bf16(qf[s], b1, s4[1], 0, 0, 0);
    }

    // p = exp(50*tanh(v/50) - 50) = exp(-100/(e^{0.04v}+1));  max is pinned at 50.
    const bool mk = sp && (i >= nst - 2);
#pragma unroll
    for (int nt = 0; nt < 2; nt++) {
      const int key = t0 + nt * 16 + l15;
#pragma unroll
      for (int j = 0; j < 4; j++) {
        float v = s4[nt][j];
        float e = __expf(v * 0.04f);
        float p = __expf(-100.f / (e + 1.f));
        if (mk && key > qrow + j) p = 0.f;
        s4[nt][j] = p;
        rs[j] += p;  // per-lane partial; cross-lane reduce deferred to end
      }
    }

    // P: C-layout -> LDS -> A-layout (per-wave slab, no block barrier needed)
#pragma unroll
    for (int nt = 0; nt < 2; nt++)
#pragma unroll
      for (int j = 0; j < 4; j++)
        Pex[wave][quad * 4 + j][nt * 16 + l15] = (__bf16)s4[nt][j];

    bf16x8 pf = *(const bf16x8*)(&Pex[wave][l15][quad * 8]);
#pragma unroll
    for (int d = 0; d < 16; d++) {
      bf16x8 vf = *(const bf16x8*)(&Vsm[buf][d * 16 + l15][quad * 8]);
      o[d] = __builtin_amdgcn_mfma_f32_16x16x32_bf16(pf, vf, o[d], 0, 0, 0);
    }
  }

  // reduce row-sums over the 16 columns held across l15 lanes
#pragma unroll
  for (int off = 1; off < 16; off <<= 1)
#pragma unroll
    for (int j = 0; j < 4; j++) rs[j] += __shfl_xor(rs[j], off);

  float* Os = Op + (size_t)sp * (2048 * 2048);
  float* Ls = Lp + sp * (2048 * 8);
  const int trow = qt * 64 + wave * 16 + quad * 4;
#pragma unroll
  for (int d = 0; d < 16; d++) {
    const int col = h * 256 + d * 16 + l15;
#pragma unroll
    for (int j = 0; j < 4; j++)
      Os[(size_t)(trow + j) * 2048 + col] = o[d][j];
  }
  if (l15 == 0) {
#pragma unroll
    for (int j = 0; j < 4; j++) Ls[(trow + j) * 8 + h] = rs[j];
  }
}

// ---------- merge the two KV-split partials: O = (O0+O1)/(l0+l1) ----------
__global__ void merge_kernel(const float* __restrict__ O0, const float* __restrict__ O1,
                             const float* __restrict__ Lp, __bf16* __restrict__ AO) {
  int f = (blockIdx.x * 256 + threadIdx.x) * 4;
  int q = f >> 11, col = f & 2047, h = col >> 8;
  float l = Lp[q * 8 + h] + Lp[2048 * 8 + q * 8 + h];
  float4 a = *(const float4*)(O0 + f);
  float4 bb = *(const float4*)(O1 + f);
  float inv = 1.f / l;
  bf16x4 o;
  o[0] = (__bf16)((a.x + bb.x) * inv);
  o[1] = (__bf16)((a.y + bb.y) * inv);
  o[2] = (__bf16)((a.z + bb.z) * inv);
  o[3] = (__bf16)((a.w + bb.w) * inv);
  *(bf16x4*)(AO + f) = o;
}

extern "C" void kernel_launch(void* const* d_in, const int* in_sizes, int n_in,
                              void* d_out, int out_size, void* d_ws, size_t ws_size,
                              hipStream_t stream) {
  const float* hidden = (const float*)d_in[0];
  const float* cosb = (const float*)d_in[1];
  const float* sinb = (const float*)d_in[2];
  // d_in[3] attention_mask: causal, reproduced analytically
  const float* wq = (const float*)d_in[4];
  const float* wk = (const float*)d_in[5];
  const float* wv = (const float*)d_in[6];
  const float* wo = (const float*)d_in[7];
  const float* qw = (const float*)d_in[8];
  const float* kw = (const float*)d_in[9];
  const float* vw = (const float*)d_in[10];
  float* outp = (float*)d_out;

  char* p = (char*)d_ws;
  __bf16* Xb = (__bf16*)p;   p += (size_t)SEQL * HID * 2;       // 16 MB (dead after GEMMs)
  __bf16* WQT = (__bf16*)p;  p += (size_t)2048 * 2048 * 2;      // 8 MB  (dead after Q GEMM)
  __bf16* WKVT = (__bf16*)p; p += (size_t)2048 * 2048 * 2;      // 8 MB  (dead after KV GEMM)
  __bf16* WOT = (__bf16*)p;  p += (size_t)2048 * 2048 * 2;      // 8 MB
  __bf16* Qp = (__bf16*)p;   p += (size_t)2048 * 2048 * 2;      // 8 MB
  __bf16* KVp = (__bf16*)p;  p += (size_t)4096 * 2048 * 2;      // 16 MB
  __bf16* VT = (__bf16*)p;   p += (size_t)4 * 256 * 4096 * 2;   // 8 MB
  __bf16* AO = (__bf16*)p;   p += (size_t)2048 * 2048 * 2;      // 8 MB
  float* Lpart = (float*)p;  p += (size_t)2 * 2048 * 8 * 4;     // 128 KB  (total ~80.1 MB)
  // fp32 partial O overlays the dead Xb / WQT+WKVT regions (16 MB each)
  float* Opart = (float*)Xb;             // split 0
  // split 1 lives at WQT (WQT+WKVT contiguous 16 MB)
  // Op pointer passed is Opart base; attn adds sp*2048*2048
  // ensure split-1 region == WQT: Xb is exactly 16 MB, so Opart + 2048*2048 == (float*)WQT. OK.

  // 1) convert inputs / weights to bf16 (weights transposed to NxK)
  cvt_bf16_kernel<<<8192, 256, 0, stream>>>(hidden, Xb);
  transpose_cvt_kernel<<<dim3(32, 32), 256, 0, stream>>>(wq, WQT, 2048, 2048);
  transpose_cvt_kernel<<<dim3(16, 32), 256, 0, stream>>>(wk, WKVT, 2048, 1024);
  transpose_cvt_kernel<<<dim3(16, 32), 256, 0, stream>>>(wv, WKVT + (size_t)1024 * 2048, 2048, 1024);
  transpose_cvt_kernel<<<dim3(32, 32), 256, 0, stream>>>(wo, WOT, 2048, 2048);

  // 2) projections: Q (128x64 tiles, 512 blocks), fused KV (128x128, 512 blocks)
  gemm_bt_kernel<2, false><<<dim3(16, 32), 256, 0, stream>>>(Xb + (size_t)2048 * 2048, WQT, Qp, 2048, 2048, 2048);
  gemm_bt_kernel<4, false><<<dim3(32, 16), 256, 0, stream>>>(Xb, WKVT, KVp, 4096, 2048, 2048);

  // 3) RMSNorm (+RoPE); Q prescaled by 2^-4; V transposed for PV fragments
  norm_rope_kernel<0><<<4096, 256, 0, stream>>>(Qp, 2048, nullptr, cosb, sinb, qw);
  norm_rope_kernel<1><<<4096, 256, 0, stream>>>(KVp, 2048, nullptr, cosb, sinb, kw);
  norm_rope_kernel<2><<<4096, 256, 0, stream>>>(KVp + 1024, 2048, VT, cosb, sinb, vw);

  // 4) flash attention, KV-split x2, fixed softmax max (softcap-bounded)
  attn_kernel<<<512, 256, 0, stream>>>(Qp, KVp, VT, Opart, Lpart);
  merge_kernel<<<4096, 256, 0, stream>>>(Opart, Opart + (size_t)2048 * 2048, Lpart, AO);

  // 5) output projection -> fp32 (128x64 tiles, 512 blocks)
  gemm_bt_kernel<2, true><<<dim3(16, 32), 256, 0, stream>>>(AO, WOT, outp, 2048, 2048, 2048);
}